// Round 2
// baseline (2472.390 us; speedup 1.0000x reference)
//
#include <hip/hip_runtime.h>
#include <hip/hip_bf16.h>

typedef __attribute__((ext_vector_type(8))) short short8;
typedef __attribute__((ext_vector_type(4))) float f32x4;

__device__ __forceinline__ float b2f(ushort u){ unsigned v = ((unsigned)u)<<16; float f; __builtin_memcpy(&f,&v,4); return f; }
__device__ __forceinline__ ushort f2b(float x){ __hip_bfloat16 h = __float2bfloat16(x); ushort u; __builtin_memcpy(&u,&h,2); return u; }
__device__ __forceinline__ float lrelu(float x){ return x >= 0.f ? x : 0.2f*x; }
__device__ __forceinline__ int   fkey(float f){ int b = __float_as_int(f); return b >= 0 ? b : (b ^ 0x7fffffff); }
__device__ __forceinline__ float funkey(int k){ int b = k >= 0 ? k : (k ^ 0x7fffffff); return __int_as_float(b); }

// ---------------- small prep kernels ----------------

__global__ void k_zero(int* degi, long N, int* cntE, float* loopS, long NE){
  long i = (long)blockIdx.x*256 + threadIdx.x;
  if (i < N) degi[i] = 0;
  if (i < NE) { cntE[i] = 0; loopS[i] = 0.f; }
}

__global__ void k_deg_val(const int* __restrict__ ve, long E2, int* degi){
  long e = (long)blockIdx.x*256 + threadIdx.x;
  if (e < E2) atomicAdd(&degi[ve[2*e+1]], 1);
}

__global__ void k_deg_ent(const int* __restrict__ ee, const float* __restrict__ lab, long E1, int* cntE, float* loopS){
  long e = (long)blockIdx.x*256 + threadIdx.x;
  if (e < E1){ int d = ee[2*e+1]; atomicAdd(&cntE[d],1); atomicAdd(&loopS[d], lab[e]); }
}

__global__ void k_dinv(const int* degi, float* dinv, long N, const int* cntE, const float* loopS, float* loopA, long NE){
  long n = (long)blockIdx.x*256 + threadIdx.x;
  if (n < N) dinv[n] = rsqrtf((float)(degi[n]+1));
  if (n < NE) loopA[n] = loopS[n] / fmaxf((float)cntE[n], 1.f);
}

// fp32 [k][n] -> bf16 [n][k]
__global__ void k_transpose(const float* __restrict__ in, ushort* __restrict__ out){
  int o = blockIdx.x*256 + threadIdx.x;           // 16384
  int k = o >> 7, n = o & 127;
  out[n*128+k] = f2b(in[k*128+n]);
}

// WvG1t[n][k] = (W[128+k,:] @ gcn1_W[:,n]) (bf16, transposed); WaG1[k][n] fp32
__global__ void k_wprod(const float* __restrict__ W, const float* __restrict__ G1, ushort* WvG1t, float* WaG1){
  int o = blockIdx.x*256 + threadIdx.x;           // 32768
  int which = o >> 14; int idx = o & 16383;
  int k = idx >> 7, n = idx & 127;
  float s = 0.f;
  if (which == 0){
    for (int j=0;j<128;++j) s += W[(128+k)*128+j] * G1[j*128+n];
    WvG1t[n*128+k] = f2b(s);
  } else {
    for (int j=0;j<128;++j) s += W[k*128+j] * G1[j*128+n];
    WaG1[k*128+n] = s;
  }
}

__global__ void k_attP(const float* __restrict__ att, const float* __restrict__ WaG1, float* attP, long NA){
  long o = (long)blockIdx.x*256 + threadIdx.x;
  if (o >= NA*128) return;
  long a = o>>7; int n = o&127;
  float s=0.f;
  for (int j=0;j<128;++j) s += att[a*128+j]*WaG1[j*128+n];
  attP[o]=s;
}

__global__ void k_csc(const float* We1, const float* ae1, const float* We2, const float* ae2, float* csc){
  int t = threadIdx.x; // 128
  __shared__ float s1[128], s2[128];
  s1[t] = We1[t]*ae1[t];
  s2[t] = We2[t]*ae2[t];
  __syncthreads();
  for (int off=64; off>0; off>>=1){ if (t<off){ s1[t]+=s1[t+off]; s2[t]+=s2[t+off]; } __syncthreads(); }
  if (t==0){ csc[0]=s1[0]; csc[1]=s2[0]; }
}

// ---------------- MFMA GEMM: C[M x 128] (bf16) = A[M x 128] (fp32) @ Bt^T ----------------
// Bt is the 128x128 weight stored TRANSPOSED ([n][k], bf16, row-major).
__global__ __launch_bounds__(256) void k_gemm(const float* __restrict__ Ap, const ushort* __restrict__ Bt,
                                              ushort* __restrict__ C, long M){
  __shared__ ushort As[128*128];
  __shared__ ushort Bs[128*128];
  int tid = threadIdx.x;
  long m0 = (long)blockIdx.x * 128;
  {
    const int4* Bg = (const int4*)Bt;
#pragma unroll
    for (int it=0; it<8; ++it){
      int chunk = tid + it*256;
      int row = chunk >> 4, c = chunk & 15;
      int4 v = Bg[chunk];
      *(int4*)&Bs[(row<<7) + (((c ^ row) & 15)<<3)] = v;
    }
  }
  {
    const float4* Ag = (const float4*)Ap;
#pragma unroll
    for (int it=0; it<16; ++it){
      int chunk = tid + it*256;                 // 4096 chunks of 4 floats, 32/row
      int row = chunk >> 5, q = chunk & 31;
      long grow = m0 + row;
      float4 v = make_float4(0.f,0.f,0.f,0.f);
      if (grow < M) v = Ag[grow*32 + q];
      ushort4 h; h.x=f2b(v.x); h.y=f2b(v.y); h.z=f2b(v.z); h.w=f2b(v.w);
      int c16 = q >> 1, half = q & 1;
      *(ushort4*)&As[(row<<7) + (((c16 ^ row)&15)<<3) + (half<<2)] = h;
    }
  }
  __syncthreads();
  int wave = tid >> 6, lane = tid & 63;
  int wm = (wave & 1) << 6, wn = (wave >> 1) << 6;
  int l15 = lane & 15, quad = lane >> 4;
  f32x4 acc[4][4] = {};
#pragma unroll
  for (int kk=0; kk<4; ++kk){
    int ch = (kk<<2) + quad;
    short8 a[4], b[4];
#pragma unroll
    for (int i=0;i<4;++i){ int r = wm + (i<<4) + l15; a[i] = *(const short8*)&As[(r<<7) + (((ch ^ r)&15)<<3)]; }
#pragma unroll
    for (int j=0;j<4;++j){ int r = wn + (j<<4) + l15; b[j] = *(const short8*)&Bs[(r<<7) + (((ch ^ r)&15)<<3)]; }
#pragma unroll
    for (int i=0;i<4;++i)
#pragma unroll
      for (int j=0;j<4;++j)
        acc[i][j] = __builtin_amdgcn_mfma_f32_16x16x32_bf16(a[i], b[j], acc[i][j], 0,0,0);
  }
#pragma unroll
  for (int i=0;i<4;++i){
#pragma unroll
    for (int r=0;r<4;++r){
      long grow = m0 + wm + (i<<4) + (quad<<2) + r;
      if (grow < M){
#pragma unroll
        for (int j=0;j<4;++j){
          int col = wn + (j<<4) + l15;
          C[grow*128 + col] = f2b(acc[i][j][r]);
        }
      }
    }
  }
}

// ---------------- assembly / aggregation kernels (one wave per row/edge) ----------------

__global__ void k_gather(const int* __restrict__ trip, const float* __restrict__ attP,
                         const ushort* __restrict__ valP, ushort* __restrict__ h0, long T, long NEnt){
  int w = threadIdx.x >> 6, lane = threadIdx.x & 63;
  long t = (long)blockIdx.x*4 + w;
  if (t >= T) return;
  int a = trip[3*t+2], v = trip[3*t+1];
  float2 ap = ((const float2*)(attP + (long)a*128))[lane];
  unsigned vp = ((const unsigned*)(valP + (long)v*128))[lane];
  ushort2 o;
  o.x = f2b(ap.x + b2f((ushort)(vp & 0xffff)));
  o.y = f2b(ap.y + b2f((ushort)(vp >> 16)));
  ((ushort2*)(h0 + (NEnt + t)*128))[lane] = o;
}

__global__ void k_gcn_init(const ushort* __restrict__ h, const float* __restrict__ dinv,
                           const float* __restrict__ bias, float* __restrict__ outA, long N){
  int w = threadIdx.x>>6, lane = threadIdx.x&63;
  long n = (long)blockIdx.x*4 + w;
  if (n >= N) return;
  float dv = dinv[n]; dv = dv*dv;
  unsigned hv = ((const unsigned*)(h + n*128))[lane];
  float2 bv = ((const float2*)bias)[lane];
  float2 o;
  o.x = dv * b2f((ushort)(hv&0xffff)) + bv.x;
  o.y = dv * b2f((ushort)(hv>>16))    + bv.y;
  ((float2*)(outA + n*128))[lane] = o;
}

__global__ void k_gcn_edges(const int* __restrict__ ve, long E, const ushort* __restrict__ h,
                            const float* __restrict__ dinv, float* __restrict__ outA, long dlimit){
  int w = threadIdx.x>>6, lane = threadIdx.x&63;
  long e = (long)blockIdx.x*4 + w;
  if (e >= E) return;
  int s = ve[2*e], d = ve[2*e+1];
  if (d >= dlimit) return;
  float wgt = dinv[s]*dinv[d];
  unsigned hv = ((const unsigned*)(h + (long)s*128))[lane];
  float* od = outA + (long)d*128;
  atomicAdd(&od[2*lane],   wgt * b2f((ushort)(hv&0xffff)));
  atomicAdd(&od[2*lane+1], wgt * b2f((ushort)(hv>>16)));
}

__global__ void k_dots(const ushort* __restrict__ hg1, const ushort* __restrict__ hg2,
                       const float* vs1, const float* vd1, const float* vs2, const float* vd2,
                       float* als1, float* ald1, float* als2, float* ald2, long NE){
  int w = threadIdx.x>>6, lane = threadIdx.x&63;
  long n = (long)blockIdx.x*4 + w;
  if (n >= NE) return;
  unsigned h1 = ((const unsigned*)(hg1 + n*128))[lane];
  unsigned h2 = ((const unsigned*)(hg2 + n*128))[lane];
  float2 u1 = ((const float2*)vs1)[lane];
  float2 u2 = ((const float2*)vd1)[lane];
  float2 u3 = ((const float2*)vs2)[lane];
  float2 u4 = ((const float2*)vd2)[lane];
  float h1a = b2f((ushort)(h1&0xffff)), h1b = b2f((ushort)(h1>>16));
  float h2a = b2f((ushort)(h2&0xffff)), h2b = b2f((ushort)(h2>>16));
  float s1 = h1a*u1.x + h1b*u1.y;
  float s2 = h1a*u2.x + h1b*u2.y;
  float s3 = h2a*u3.x + h2b*u3.y;
  float s4 = h2a*u4.x + h2b*u4.y;
  for (int o=32; o>0; o>>=1){
    s1 += __shfl_down(s1,o); s2 += __shfl_down(s2,o);
    s3 += __shfl_down(s3,o); s4 += __shfl_down(s4,o);
  }
  if (lane==0){ als1[n]=s1; ald1[n]=s2; als2[n]=s3; ald2[n]=s4; }
}

__global__ void k_gat_self(const float* als1,const float* ald1,const float* als2,const float* ald2,
                           const float* loopA, const float* csc, int* mi1, int* mi2, long NE){
  long n = (long)blockIdx.x*256 + threadIdx.x;
  if (n>=NE) return;
  mi1[n] = fkey(lrelu(als1[n]+ald1[n]+csc[0]*loopA[n]));
  mi2[n] = fkey(lrelu(als2[n]+ald2[n]+csc[1]*loopA[n]));
}

__global__ void k_gat_alpha(const int* __restrict__ ee, const float* __restrict__ lab, long E1,
    const float* __restrict__ als1, const float* __restrict__ ald1,
    const float* __restrict__ als2, const float* __restrict__ ald2,
    const float* csc, float* alpha1, float* alpha2, int* mi1, int* mi2){
  long e = (long)blockIdx.x*256 + threadIdx.x;
  if (e >= E1) return;
  int s = ee[2*e], d = ee[2*e+1];
  float l = lab[e];
  float a1 = lrelu(als1[s]+ald1[d]+csc[0]*l);
  float a2 = lrelu(als2[s]+ald2[d]+csc[1]*l);
  alpha1[e]=a1; alpha2[e]=a2;
  atomicMax(&mi1[d], fkey(a1));
  atomicMax(&mi2[d], fkey(a2));
}

__global__ void k_gat_zinit(const float* als1,const float* ald1,const float* als2,const float* ald2,
    const float* loopA, const float* csc, const int* mi1, const int* mi2, float* z1, float* z2, long NE){
  long n = (long)blockIdx.x*256 + threadIdx.x;
  if (n>=NE) return;
  float a1 = lrelu(als1[n]+ald1[n]+csc[0]*loopA[n]);
  float a2 = lrelu(als2[n]+ald2[n]+csc[1]*loopA[n]);
  z1[n] = expf(a1 - funkey(mi1[n]));
  z2[n] = expf(a2 - funkey(mi2[n]));
}

__global__ void k_gat_zedge(const int* __restrict__ ee, long E1, const float* __restrict__ alpha1,
    const float* __restrict__ alpha2, const int* mi1, const int* mi2, float* z1, float* z2){
  long e = (long)blockIdx.x*256 + threadIdx.x;
  if (e>=E1) return;
  int d = ee[2*e+1];
  atomicAdd(&z1[d], expf(alpha1[e]-funkey(mi1[d])));
  atomicAdd(&z2[d], expf(alpha2[e]-funkey(mi2[d])));
}

__global__ void k_gat_outinit(const ushort* __restrict__ hg1, const ushort* __restrict__ hg2,
    const float* als1,const float* ald1,const float* als2,const float* ald2,
    const float* loopA, const float* csc, const int* mi1, const int* mi2,
    const float* z1, const float* z2, const float* b1, const float* b2v,
    float* __restrict__ g_acc, long NE){
  int w = threadIdx.x>>6, lane=threadIdx.x&63;
  long n = (long)blockIdx.x*4 + w;
  if (n>=NE) return;
  float a1 = lrelu(als1[n]+ald1[n]+csc[0]*loopA[n]);
  float a2 = lrelu(als2[n]+ald2[n]+csc[1]*loopA[n]);
  float w1 = expf(a1 - funkey(mi1[n])) / (z1[n]+1e-16f);
  float w2 = expf(a2 - funkey(mi2[n])) / (z2[n]+1e-16f);
  unsigned h1 = ((const unsigned*)(hg1+n*128))[lane];
  unsigned h2 = ((const unsigned*)(hg2+n*128))[lane];
  float2 ub1 = ((const float2*)b1)[lane];
  float2 ub2 = ((const float2*)b2v)[lane];
  float2 o;
  o.x = ub1.x + ub2.x + w1*b2f((ushort)(h1&0xffff)) + w2*b2f((ushort)(h2&0xffff));
  o.y = ub1.y + ub2.y + w1*b2f((ushort)(h1>>16))    + w2*b2f((ushort)(h2>>16));
  ((float2*)(g_acc+n*128))[lane] = o;
}

__global__ void k_gat_outedge(const int* __restrict__ ee, long E1, const ushort* __restrict__ hg1,
    const ushort* __restrict__ hg2, const float* __restrict__ alpha1, const float* __restrict__ alpha2,
    const int* mi1, const int* mi2, const float* z1, const float* z2, float* __restrict__ g_acc){
  int w = threadIdx.x>>6, lane=threadIdx.x&63;
  long e = (long)blockIdx.x*4 + w;
  if (e>=E1) return;
  int s = ee[2*e], d = ee[2*e+1];
  float w1 = expf(alpha1[e]-funkey(mi1[d]))/(z1[d]+1e-16f);
  float w2 = expf(alpha2[e]-funkey(mi2[d]))/(z2[d]+1e-16f);
  unsigned h1 = ((const unsigned*)(hg1+(long)s*128))[lane];
  unsigned h2 = ((const unsigned*)(hg2+(long)s*128))[lane];
  float* od = g_acc + (long)d*128;
  atomicAdd(&od[2*lane],   w1*b2f((ushort)(h1&0xffff)) + w2*b2f((ushort)(h2&0xffff)));
  atomicAdd(&od[2*lane+1], w1*b2f((ushort)(h1>>16))    + w2*b2f((ushort)(h2>>16)));
}

__global__ void k_final(const float* __restrict__ g_acc, const float* __restrict__ entf,
                        float* __restrict__ out, long NE){
  int w=threadIdx.x>>6, lane=threadIdx.x&63;
  long n=(long)blockIdx.x*4+w;
  if(n>=NE) return;
  float2 g = ((const float2*)(g_acc+n*128))[lane];
  float2 ef = ((const float2*)(entf+n*128))[lane];
  float2 o; o.x = g.x + ef.x; o.y = g.y + ef.y;
  ((float2*)(out+n*128))[lane] = o;
}

// ---------------- host ----------------

extern "C" void kernel_launch(void* const* d_in, const int* in_sizes, int n_in,
                              void* d_out, int out_size, void* d_ws, size_t ws_size,
                              hipStream_t stream) {
  const int*   trip = (const int*)d_in[0];
  const int*   ee   = (const int*)d_in[1];
  const float* eel  = (const float*)d_in[2];
  const int*   ve   = (const int*)d_in[3];
  const float* att  = (const float*)d_in[5];
  const float* valf = (const float*)d_in[6];
  const float* entf = (const float*)d_in[7];
  const float* W    = (const float*)d_in[8];
  const float* G1   = (const float*)d_in[9];
  const float* g1b  = (const float*)d_in[10];
  const float* G2   = (const float*)d_in[11];
  const float* g2b  = (const float*)d_in[12];
  const float* Wl1  = (const float*)d_in[13];
  const float* as1v = (const float*)d_in[14];
  const float* ad1v = (const float*)d_in[15];
  const float* We1  = (const float*)d_in[16];
  const float* ae1  = (const float*)d_in[17];
  const float* b1   = (const float*)d_in[18];
  const float* Wl2  = (const float*)d_in[19];
  const float* as2v = (const float*)d_in[20];
  const float* ad2v = (const float*)d_in[21];
  const float* We2  = (const float*)d_in[22];
  const float* ae2  = (const float*)d_in[23];
  const float* b2   = (const float*)d_in[24];

  long T    = in_sizes[0]/3;
  long E1   = in_sizes[1]/2;
  long E2   = in_sizes[3]/2;
  long NA   = in_sizes[5]/128;
  long NV   = in_sizes[6]/128;
  long NEnt = in_sizes[7]/128;
  long N    = NEnt + T;

  size_t off = 0;
  auto alloc = [&](size_t bytes)->char*{
    char* p = (char*)d_ws + off; off = (off + bytes + 255) & ~(size_t)255; return p;
  };
  float*  A     = (float*)alloc((size_t)N*128*4);    // fp32 node buffer (nodes1 / nodes2 / g_acc)
  ushort* B     = (ushort*)alloc((size_t)N*128*2);   // bf16 h buffer (h0 / h2 / hg1,hg2)
  float*  attP  = (float*)alloc((size_t)NA*128*4);
  int*    degi  = (int*)alloc(N*4);
  float*  dinv  = (float*)alloc(N*4);
  int*    cntE  = (int*)alloc(NEnt*4);
  float*  loopS = (float*)alloc(NEnt*4);
  float*  loopA = (float*)alloc(NEnt*4);
  float*  als1  = (float*)alloc(NEnt*4);
  float*  ald1  = (float*)alloc(NEnt*4);
  float*  als2  = (float*)alloc(NEnt*4);
  float*  ald2  = (float*)alloc(NEnt*4);
  int*    mi1   = (int*)alloc(NEnt*4);
  int*    mi2   = (int*)alloc(NEnt*4);
  float*  z1    = (float*)alloc(NEnt*4);
  float*  z2    = (float*)alloc(NEnt*4);
  float*  alpha1= (float*)alloc(E1*4);
  float*  alpha2= (float*)alloc(E1*4);
  ushort* WvG1t = (ushort*)alloc(16384*2);
  float*  WaG1  = (float*)alloc(16384*4);
  ushort* G1t   = (ushort*)alloc(16384*2);
  ushort* G2t   = (ushort*)alloc(16384*2);
  ushort* Wl1t  = (ushort*)alloc(16384*2);
  ushort* Wl2t  = (ushort*)alloc(16384*2);
  float*  csc   = (float*)alloc(256);

  ushort* valP  = (ushort*)A;           // bf16, lives in A before A's fp32 use
  float*  g_acc = A + (size_t)NEnt*128; // rows [NEnt, 2*NEnt) of A
  ushort* hg1   = B;
  ushort* hg2   = B + (size_t)NEnt*128;

  auto cdiv = [](long a, long b)->int{ return (int)((a + b - 1)/b); };

  // degrees / loop_attr / weight prep
  k_zero<<<cdiv(N,256),256,0,stream>>>(degi, N, cntE, loopS, NEnt);
  k_deg_val<<<cdiv(E2,256),256,0,stream>>>(ve, E2, degi);
  k_deg_ent<<<cdiv(E1,256),256,0,stream>>>(ee, eel, E1, cntE, loopS);
  k_dinv<<<cdiv(N,256),256,0,stream>>>(degi, dinv, N, cntE, loopS, loopA, NEnt);
  k_transpose<<<64,256,0,stream>>>(G1, G1t);
  k_transpose<<<64,256,0,stream>>>(G2, G2t);
  k_transpose<<<64,256,0,stream>>>(Wl1, Wl1t);
  k_transpose<<<64,256,0,stream>>>(Wl2, Wl2t);
  k_wprod<<<128,256,0,stream>>>(W, G1, WvG1t, WaG1);
  k_attP<<<cdiv(NA*128,256),256,0,stream>>>(att, WaG1, attP, NA);
  k_csc<<<1,128,0,stream>>>(We1, ae1, We2, ae2, csc);

  // h0 = nodes0 @ gcn1_W  (folded)
  k_gemm<<<cdiv(NV,128),256,0,stream>>>(valf, WvG1t, valP, NV);
  k_gemm<<<cdiv(NEnt,128),256,0,stream>>>(entf, G1t, B, NEnt);
  k_gather<<<cdiv(T,4),256,0,stream>>>(trip, attP, valP, B, T, NEnt);

  // GCN1 (full N)
  k_gcn_init<<<cdiv(N,4),256,0,stream>>>(B, dinv, g1b, A, N);
  k_gcn_edges<<<cdiv(E2,4),256,0,stream>>>(ve, E2, B, dinv, A, N);

  // GCN2 (only dst < NEnt needed)
  k_gemm<<<cdiv(N,128),256,0,stream>>>(A, G2t, B, N);            // h2 (bf16)
  k_gcn_init<<<cdiv(NEnt,4),256,0,stream>>>(B, dinv, g2b, A, NEnt);   // nodes2 into A[:NEnt]
  k_gcn_edges<<<cdiv(E2,4),256,0,stream>>>(ve, E2, B, dinv, A, NEnt);

  // GAT (both layers fused; only rows < NEnt)
  k_gemm<<<cdiv(NEnt,128),256,0,stream>>>(A, Wl1t, hg1, NEnt);
  k_gemm<<<cdiv(NEnt,128),256,0,stream>>>(A, Wl2t, hg2, NEnt);
  k_dots<<<cdiv(NEnt,4),256,0,stream>>>(hg1, hg2, as1v, ad1v, as2v, ad2v, als1, ald1, als2, ald2, NEnt);
  k_gat_self<<<cdiv(NEnt,256),256,0,stream>>>(als1, ald1, als2, ald2, loopA, csc, mi1, mi2, NEnt);
  k_gat_alpha<<<cdiv(E1,256),256,0,stream>>>(ee, eel, E1, als1, ald1, als2, ald2, csc, alpha1, alpha2, mi1, mi2);
  k_gat_zinit<<<cdiv(NEnt,256),256,0,stream>>>(als1, ald1, als2, ald2, loopA, csc, mi1, mi2, z1, z2, NEnt);
  k_gat_zedge<<<cdiv(E1,256),256,0,stream>>>(ee, E1, alpha1, alpha2, mi1, mi2, z1, z2);
  k_gat_outinit<<<cdiv(NEnt,4),256,0,stream>>>(hg1, hg2, als1, ald1, als2, ald2, loopA, csc,
                                               mi1, mi2, z1, z2, b1, b2, g_acc, NEnt);
  k_gat_outedge<<<cdiv(E1,4),256,0,stream>>>(ee, E1, hg1, hg2, alpha1, alpha2, mi1, mi2, z1, z2, g_acc);

  k_final<<<cdiv(NEnt,4),256,0,stream>>>(g_acc, entf, (float*)d_out, NEnt);
}

// Round 3
// 1186.118 us; speedup vs baseline: 2.0844x; 2.0844x over previous
//
#include <hip/hip_runtime.h>
#include <hip/hip_bf16.h>

typedef __attribute__((ext_vector_type(8))) short short8;
typedef __attribute__((ext_vector_type(4))) float f32x4;

__device__ __forceinline__ float b2f(ushort u){ unsigned v = ((unsigned)u)<<16; float f; __builtin_memcpy(&f,&v,4); return f; }
__device__ __forceinline__ ushort f2b(float x){ __hip_bfloat16 h = __float2bfloat16(x); ushort u; __builtin_memcpy(&u,&h,2); return u; }
__device__ __forceinline__ float lrelu(float x){ return x >= 0.f ? x : 0.2f*x; }

// ---------------- small prep kernels ----------------

__global__ void k_zero(int* degi, long N, int* cntE, float* loopS, long NE){
  long i = (long)blockIdx.x*256 + threadIdx.x;
  if (i < N) degi[i] = 0;
  if (i < NE) { cntE[i] = 0; loopS[i] = 0.f; }
}

__global__ void k_deg_val(const int* __restrict__ ve, long E2, int* degi){
  long e = (long)blockIdx.x*256 + threadIdx.x;
  if (e < E2) atomicAdd(&degi[ve[2*e+1]], 1);
}

__global__ void k_deg_ent(const int* __restrict__ ee, const float* __restrict__ lab, long E1, int* cntE, float* loopS){
  long e = (long)blockIdx.x*256 + threadIdx.x;
  if (e < E1){ int d = ee[2*e+1]; atomicAdd(&cntE[d],1); atomicAdd(&loopS[d], lab[e]); }
}

__global__ void k_dinv(const int* degi, float* dinv, long N, const int* cntE, const float* loopS, float* loopA, long NE){
  long n = (long)blockIdx.x*256 + threadIdx.x;
  if (n < N) dinv[n] = rsqrtf((float)(degi[n]+1));
  if (n < NE) loopA[n] = loopS[n] / fmaxf((float)cntE[n], 1.f);
}

// ---------------- prefix-sum (CSR rowptr) ----------------
// 1024 items/block (256 thr x 4). intra-block exclusive into ps, block sum into bsum.
__global__ void k_scan1(const int* __restrict__ deg, long L, int* __restrict__ ps, int* __restrict__ bsum){
  __shared__ int s[256];
  long base = (long)blockIdx.x*1024;
  int t = threadIdx.x;
  int v[4]; int sum = 0;
#pragma unroll
  for (int i=0;i<4;++i){ long idx = base + t*4 + i; v[i] = (idx<L) ? deg[idx] : 0; sum += v[i]; }
  s[t] = sum; __syncthreads();
  for (int off=1; off<256; off<<=1){
    int x = 0;
    if (t>=off) x = s[t-off];
    __syncthreads();
    if (t>=off) s[t] += x;
    __syncthreads();
  }
  int run = s[t] - sum;
#pragma unroll
  for (int i=0;i<4;++i){ long idx = base + t*4 + i; if (idx<L) ps[idx] = run; run += v[i]; }
  if (t==255) bsum[blockIdx.x] = s[255];
}

// single block: exclusive scan of nb (<512) block sums
__global__ void k_scan2(const int* __restrict__ bsum, int* __restrict__ boff, int nb){
  __shared__ int s[512];
  int t = threadIdx.x;
  int v = (t<nb) ? bsum[t] : 0;
  s[t] = v; __syncthreads();
  for (int off=1; off<512; off<<=1){
    int x = 0;
    if (t>=off) x = s[t-off];
    __syncthreads();
    if (t>=off) s[t] += x;
    __syncthreads();
  }
  if (t<nb) boff[t] = s[t] - v;
}

__global__ void k_scan3(int* __restrict__ ps, int* __restrict__ cur, const int* __restrict__ boff, long L, int E){
  long i = (long)blockIdx.x*256 + threadIdx.x;
  if (i < L){ int v = ps[i] + boff[i>>10]; ps[i] = v; cur[i] = v; }
  if (i == L) ps[L] = E;
}

__global__ void k_scatter_val(const int* __restrict__ ve, long E2, const float* __restrict__ dinv,
                              int* __restrict__ cur, int2* __restrict__ pk){
  long e = (long)blockIdx.x*256 + threadIdx.x;
  if (e >= E2) return;
  int s = ve[2*e], d = ve[2*e+1];
  int pos = atomicAdd(&cur[d], 1);
  int2 p; p.x = s; p.y = __float_as_int(dinv[s]);
  pk[pos] = p;
}

__global__ void k_scatter_ent(const int* __restrict__ ee, const float* __restrict__ lab, long E1,
                              int* __restrict__ cur, int2* __restrict__ pk){
  long e = (long)blockIdx.x*256 + threadIdx.x;
  if (e >= E1) return;
  int s = ee[2*e], d = ee[2*e+1];
  int pos = atomicAdd(&cur[d], 1);
  int2 p; p.x = s; p.y = __float_as_int(lab[e]);
  pk[pos] = p;
}

// ---------------- weight prep ----------------

// fp32 [k][n] -> bf16 [n][k]
__global__ void k_transpose(const float* __restrict__ in, ushort* __restrict__ out){
  int o = blockIdx.x*256 + threadIdx.x;           // 16384
  int k = o >> 7, n = o & 127;
  out[n*128+k] = f2b(in[k*128+n]);
}

// WvG1t[n][k] = (W[128+k,:] @ gcn1_W[:,n]) (bf16, transposed); WaG1[k][n] fp32
__global__ void k_wprod(const float* __restrict__ W, const float* __restrict__ G1, ushort* WvG1t, float* WaG1){
  int o = blockIdx.x*256 + threadIdx.x;           // 32768
  int which = o >> 14; int idx = o & 16383;
  int k = idx >> 7, n = idx & 127;
  float s = 0.f;
  if (which == 0){
    for (int j=0;j<128;++j) s += W[(128+k)*128+j] * G1[j*128+n];
    WvG1t[n*128+k] = f2b(s);
  } else {
    for (int j=0;j<128;++j) s += W[k*128+j] * G1[j*128+n];
    WaG1[k*128+n] = s;
  }
}

__global__ void k_attP(const float* __restrict__ att, const float* __restrict__ WaG1, float* attP, long NA){
  long o = (long)blockIdx.x*256 + threadIdx.x;
  if (o >= NA*128) return;
  long a = o>>7; int n = o&127;
  float s=0.f;
  for (int j=0;j<128;++j) s += att[a*128+j]*WaG1[j*128+n];
  attP[o]=s;
}

__global__ void k_csc(const float* We1, const float* ae1, const float* We2, const float* ae2, float* csc){
  int t = threadIdx.x; // 128
  __shared__ float s1[128], s2[128];
  s1[t] = We1[t]*ae1[t];
  s2[t] = We2[t]*ae2[t];
  __syncthreads();
  for (int off=64; off>0; off>>=1){ if (t<off){ s1[t]+=s1[t+off]; s2[t]+=s2[t+off]; } __syncthreads(); }
  if (t==0){ csc[0]=s1[0]; csc[1]=s2[0]; }
}

// ---------------- MFMA GEMM: C[M x 128] (bf16) = A[M x 128] (fp32) @ Bt^T ----------------
__global__ __launch_bounds__(256) void k_gemm(const float* __restrict__ Ap, const ushort* __restrict__ Bt,
                                              ushort* __restrict__ C, long M){
  __shared__ ushort As[128*128];
  __shared__ ushort Bs[128*128];
  int tid = threadIdx.x;
  long m0 = (long)blockIdx.x * 128;
  {
    const int4* Bg = (const int4*)Bt;
#pragma unroll
    for (int it=0; it<8; ++it){
      int chunk = tid + it*256;
      int row = chunk >> 4, c = chunk & 15;
      int4 v = Bg[chunk];
      *(int4*)&Bs[(row<<7) + (((c ^ row) & 15)<<3)] = v;
    }
  }
  {
    const float4* Ag = (const float4*)Ap;
#pragma unroll
    for (int it=0; it<16; ++it){
      int chunk = tid + it*256;
      int row = chunk >> 5, q = chunk & 31;
      long grow = m0 + row;
      float4 v = make_float4(0.f,0.f,0.f,0.f);
      if (grow < M) v = Ag[grow*32 + q];
      ushort4 h; h.x=f2b(v.x); h.y=f2b(v.y); h.z=f2b(v.z); h.w=f2b(v.w);
      int c16 = q >> 1, half = q & 1;
      *(ushort4*)&As[(row<<7) + (((c16 ^ row)&15)<<3) + (half<<2)] = h;
    }
  }
  __syncthreads();
  int wave = tid >> 6, lane = tid & 63;
  int wm = (wave & 1) << 6, wn = (wave >> 1) << 6;
  int l15 = lane & 15, quad = lane >> 4;
  f32x4 acc[4][4] = {};
#pragma unroll
  for (int kk=0; kk<4; ++kk){
    int ch = (kk<<2) + quad;
    short8 a[4], b[4];
#pragma unroll
    for (int i=0;i<4;++i){ int r = wm + (i<<4) + l15; a[i] = *(const short8*)&As[(r<<7) + (((ch ^ r)&15)<<3)]; }
#pragma unroll
    for (int j=0;j<4;++j){ int r = wn + (j<<4) + l15; b[j] = *(const short8*)&Bs[(r<<7) + (((ch ^ r)&15)<<3)]; }
#pragma unroll
    for (int i=0;i<4;++i)
#pragma unroll
      for (int j=0;j<4;++j)
        acc[i][j] = __builtin_amdgcn_mfma_f32_16x16x32_bf16(a[i], b[j], acc[i][j], 0,0,0);
  }
#pragma unroll
  for (int i=0;i<4;++i){
#pragma unroll
    for (int r=0;r<4;++r){
      long grow = m0 + wm + (i<<4) + (quad<<2) + r;
      if (grow < M){
#pragma unroll
        for (int j=0;j<4;++j){
          int col = wn + (j<<4) + l15;
          C[grow*128 + col] = f2b(acc[i][j][r]);
        }
      }
    }
  }
}

// ---------------- assembly / gather kernels ----------------

__global__ void k_gather(const int* __restrict__ trip, const float* __restrict__ attP,
                         const ushort* __restrict__ valP, ushort* __restrict__ h0, long T, long NEnt){
  int w = threadIdx.x >> 6, lane = threadIdx.x & 63;
  long t = (long)blockIdx.x*4 + w;
  if (t >= T) return;
  int a = trip[3*t+2], v = trip[3*t+1];
  float2 ap = ((const float2*)(attP + (long)a*128))[lane];
  unsigned vp = ((const unsigned*)(valP + (long)v*128))[lane];
  ushort2 o;
  o.x = f2b(ap.x + b2f((ushort)(vp & 0xffff)));
  o.y = f2b(ap.y + b2f((ushort)(vp >> 16)));
  ((ushort2*)(h0 + (NEnt + t)*128))[lane] = o;
}

// GCN layer via CSR gather: out[d] = dinv[d]^2*h[d] + b + sum_e dinv[s]*dinv[d]*h[s]
__global__ void k_gcn_csr(const int* __restrict__ rp, const int2* __restrict__ pk,
                          const ushort* __restrict__ h, const float* __restrict__ dinv,
                          const float* __restrict__ bias, float* __restrict__ outA, long R){
  int w = threadIdx.x>>6, lane = threadIdx.x&63;
  long d = (long)blockIdx.x*4 + w;
  if (d >= R) return;
  int r0 = rp[d], r1 = rp[d+1];
  float dv = dinv[d];
  unsigned hv = ((const unsigned*)(h + d*128))[lane];
  float2 bv = ((const float2*)bias)[lane];
  float ax = dv*dv*b2f((ushort)(hv&0xffff)) + bv.x;
  float ay = dv*dv*b2f((ushort)(hv>>16))    + bv.y;
  for (int e = r0; e < r1; ++e){
    int2 p = pk[e];
    float wgt = dv * __int_as_float(p.y);
    unsigned sv = ((const unsigned*)(h + (long)p.x*128))[lane];
    ax += wgt * b2f((ushort)(sv&0xffff));
    ay += wgt * b2f((ushort)(sv>>16));
  }
  ((float2*)(outA + d*128))[lane] = make_float2(ax, ay);
}

// Fused GAT (both layers) via CSR gather; writes final output (+biases +ent_feats).
__global__ void k_gat_csr(const int* __restrict__ rp, const int2* __restrict__ pk,
      const ushort* __restrict__ hg1, const ushort* __restrict__ hg2,
      const float* __restrict__ als1, const float* __restrict__ ald1,
      const float* __restrict__ als2, const float* __restrict__ ald2,
      const float* __restrict__ loopA, const float* __restrict__ csc,
      const float* __restrict__ b1, const float* __restrict__ b2v,
      const float* __restrict__ entf, float* __restrict__ out, long R){
  int w = threadIdx.x>>6, lane = threadIdx.x&63;
  long d = (long)blockIdx.x*4 + w;
  if (d >= R) return;
  int r0 = rp[d], r1 = rp[d+1];
  int ne = r1 - r0;
  float c1 = csc[0], c2 = csc[1];
  float al1d = ald1[d], al2d = ald2[d];
  float a1s = lrelu(als1[d] + al1d + c1*loopA[d]);
  float a2s = lrelu(als2[d] + al2d + c2*loopA[d]);
  float m1 = a1s, m2 = a2s;
  // pass 1: segment max (lane-parallel over edges)
  for (int base = 0; base < ne; base += 64){
    int i = base + lane;
    float a1 = -1e30f, a2 = -1e30f;
    if (i < ne){
      int2 p = pk[r0+i];
      float lab = __int_as_float(p.y);
      a1 = lrelu(als1[p.x] + al1d + c1*lab);
      a2 = lrelu(als2[p.x] + al2d + c2*lab);
    }
    for (int o=32;o>0;o>>=1){ a1 = fmaxf(a1, __shfl_down(a1,o)); a2 = fmaxf(a2, __shfl_down(a2,o)); }
    a1 = __shfl(a1, 0); a2 = __shfl(a2, 0);
    m1 = fmaxf(m1, a1); m2 = fmaxf(m2, a2);
  }
  // pass 2: weights + aggregation
  float e1s = __expf(a1s - m1), e2s = __expf(a2s - m2);
  float z1 = e1s, z2 = e2s;
  unsigned h1d = ((const unsigned*)(hg1 + d*128))[lane];
  unsigned h2d = ((const unsigned*)(hg2 + d*128))[lane];
  float acc1x = e1s*b2f((ushort)(h1d&0xffff)), acc1y = e1s*b2f((ushort)(h1d>>16));
  float acc2x = e2s*b2f((ushort)(h2d&0xffff)), acc2y = e2s*b2f((ushort)(h2d>>16));
  for (int base = 0; base < ne; base += 64){
    int i = base + lane;
    float e1 = 0.f, e2 = 0.f; int src = 0;
    if (i < ne){
      int2 p = pk[r0+i];
      float lab = __int_as_float(p.y);
      src = p.x;
      e1 = __expf(lrelu(als1[src] + al1d + c1*lab) - m1);
      e2 = __expf(lrelu(als2[src] + al2d + c2*lab) - m2);
    }
    int lim = (ne - base < 64) ? (ne - base) : 64;
    for (int j = 0; j < lim; ++j){
      float f1 = __shfl(e1, j), f2 = __shfl(e2, j);
      int   sj = __shfl(src, j);
      z1 += f1; z2 += f2;
      unsigned v1 = ((const unsigned*)(hg1 + (long)sj*128))[lane];
      unsigned v2 = ((const unsigned*)(hg2 + (long)sj*128))[lane];
      acc1x += f1*b2f((ushort)(v1&0xffff)); acc1y += f1*b2f((ushort)(v1>>16));
      acc2x += f2*b2f((ushort)(v2&0xffff)); acc2y += f2*b2f((ushort)(v2>>16));
    }
  }
  float i1 = 1.f/(z1+1e-16f), i2 = 1.f/(z2+1e-16f);
  float2 bv1 = ((const float2*)b1)[lane];
  float2 bv2 = ((const float2*)b2v)[lane];
  float2 ef  = ((const float2*)(entf + d*128))[lane];
  float ox = acc1x*i1 + acc2x*i2 + bv1.x + bv2.x + ef.x;
  float oy = acc1y*i1 + acc2y*i2 + bv1.y + bv2.y + ef.y;
  ((float2*)(out + d*128))[lane] = make_float2(ox, oy);
}

// per-node attention dots: als = h·a_src, ald = h·a_dst  (both layers)
__global__ void k_dots(const ushort* __restrict__ hg1, const ushort* __restrict__ hg2,
                       const float* vs1, const float* vd1, const float* vs2, const float* vd2,
                       float* als1, float* ald1, float* als2, float* ald2, long NE){
  int w = threadIdx.x>>6, lane = threadIdx.x&63;
  long n = (long)blockIdx.x*4 + w;
  if (n >= NE) return;
  unsigned h1 = ((const unsigned*)(hg1 + n*128))[lane];
  unsigned h2 = ((const unsigned*)(hg2 + n*128))[lane];
  float2 u1 = ((const float2*)vs1)[lane];
  float2 u2 = ((const float2*)vd1)[lane];
  float2 u3 = ((const float2*)vs2)[lane];
  float2 u4 = ((const float2*)vd2)[lane];
  float h1a = b2f((ushort)(h1&0xffff)), h1b = b2f((ushort)(h1>>16));
  float h2a = b2f((ushort)(h2&0xffff)), h2b = b2f((ushort)(h2>>16));
  float s1 = h1a*u1.x + h1b*u1.y;
  float s2 = h1a*u2.x + h1b*u2.y;
  float s3 = h2a*u3.x + h2b*u3.y;
  float s4 = h2a*u4.x + h2b*u4.y;
  for (int o=32; o>0; o>>=1){
    s1 += __shfl_down(s1,o); s2 += __shfl_down(s2,o);
    s3 += __shfl_down(s3,o); s4 += __shfl_down(s4,o);
  }
  if (lane==0){ als1[n]=s1; ald1[n]=s2; als2[n]=s3; ald2[n]=s4; }
}

// ---------------- host ----------------

extern "C" void kernel_launch(void* const* d_in, const int* in_sizes, int n_in,
                              void* d_out, int out_size, void* d_ws, size_t ws_size,
                              hipStream_t stream) {
  const int*   trip = (const int*)d_in[0];
  const int*   ee   = (const int*)d_in[1];
  const float* eel  = (const float*)d_in[2];
  const int*   ve   = (const int*)d_in[3];
  const float* att  = (const float*)d_in[5];
  const float* valf = (const float*)d_in[6];
  const float* entf = (const float*)d_in[7];
  const float* W    = (const float*)d_in[8];
  const float* G1   = (const float*)d_in[9];
  const float* g1b  = (const float*)d_in[10];
  const float* G2   = (const float*)d_in[11];
  const float* g2b  = (const float*)d_in[12];
  const float* Wl1  = (const float*)d_in[13];
  const float* as1v = (const float*)d_in[14];
  const float* ad1v = (const float*)d_in[15];
  const float* We1  = (const float*)d_in[16];
  const float* ae1  = (const float*)d_in[17];
  const float* b1   = (const float*)d_in[18];
  const float* Wl2  = (const float*)d_in[19];
  const float* as2v = (const float*)d_in[20];
  const float* ad2v = (const float*)d_in[21];
  const float* We2  = (const float*)d_in[22];
  const float* ae2  = (const float*)d_in[23];
  const float* b2   = (const float*)d_in[24];

  long T    = in_sizes[0]/3;
  long E1   = in_sizes[1]/2;
  long E2   = in_sizes[3]/2;
  long NA   = in_sizes[5]/128;
  long NV   = in_sizes[6]/128;
  long NEnt = in_sizes[7]/128;
  long N    = NEnt + T;

  size_t off = 0;
  auto alloc = [&](size_t bytes)->char*{
    char* p = (char*)d_ws + off; off = (off + bytes + 255) & ~(size_t)255; return p;
  };
  float*  A     = (float*)alloc((size_t)N*128*4);    // fp32 node buffer (nodes1 / nodes2)
  ushort* B     = (ushort*)alloc((size_t)N*128*2);   // bf16 h buffer (h0 / h2 / hg1,hg2)
  float*  attP  = (float*)alloc((size_t)NA*128*4);
  int*    degi  = (int*)alloc(N*4);
  float*  dinv  = (float*)alloc(N*4);
  int*    cntE  = (int*)alloc(NEnt*4);
  float*  loopS = (float*)alloc(NEnt*4);
  float*  loopA = (float*)alloc(NEnt*4);
  float*  als1  = (float*)alloc(NEnt*4);
  float*  ald1  = (float*)alloc(NEnt*4);
  float*  als2  = (float*)alloc(NEnt*4);
  float*  ald2  = (float*)alloc(NEnt*4);
  int*    rpV   = (int*)alloc((N+1)*4);
  int*    curV  = (int*)alloc(N*4);
  int2*   pkV   = (int2*)alloc((size_t)E2*8);
  int*    rpE   = (int*)alloc((NEnt+1)*4);
  int*    curE  = (int*)alloc(NEnt*4);
  int2*   pkE   = (int2*)alloc((size_t)E1*8);
  int*    bsumV = (int*)alloc(512*4);
  int*    boffV = (int*)alloc(512*4);
  int*    bsumE = (int*)alloc(512*4);
  int*    boffE = (int*)alloc(512*4);
  ushort* WvG1t = (ushort*)alloc(16384*2);
  float*  WaG1  = (float*)alloc(16384*4);
  ushort* G1t   = (ushort*)alloc(16384*2);
  ushort* G2t   = (ushort*)alloc(16384*2);
  ushort* Wl1t  = (ushort*)alloc(16384*2);
  ushort* Wl2t  = (ushort*)alloc(16384*2);
  float*  csc   = (float*)alloc(256);

  ushort* valP  = (ushort*)A;           // bf16, lives in A before A's fp32 use
  ushort* hg1   = B;
  ushort* hg2   = B + (size_t)NEnt*128;

  auto cdiv = [](long a, long b)->int{ return (int)((a + b - 1)/b); };
  int nbV = cdiv(N, 1024), nbE = cdiv(NEnt, 1024);

  // degrees / loop_attr
  k_zero<<<cdiv(N,256),256,0,stream>>>(degi, N, cntE, loopS, NEnt);
  k_deg_val<<<cdiv(E2,256),256,0,stream>>>(ve, E2, degi);
  k_deg_ent<<<cdiv(E1,256),256,0,stream>>>(ee, eel, E1, cntE, loopS);
  k_dinv<<<cdiv(N,256),256,0,stream>>>(degi, dinv, N, cntE, loopS, loopA, NEnt);

  // CSR build (val graph over N, ent graph over NEnt)
  k_scan1<<<nbV,256,0,stream>>>(degi, N, rpV, bsumV);
  k_scan2<<<1,512,0,stream>>>(bsumV, boffV, nbV);
  k_scan3<<<cdiv(N+1,256),256,0,stream>>>(rpV, curV, boffV, N, (int)E2);
  k_scan1<<<nbE,256,0,stream>>>(cntE, NEnt, rpE, bsumE);
  k_scan2<<<1,512,0,stream>>>(bsumE, boffE, nbE);
  k_scan3<<<cdiv(NEnt+1,256),256,0,stream>>>(rpE, curE, boffE, NEnt, (int)E1);
  k_scatter_val<<<cdiv(E2,256),256,0,stream>>>(ve, E2, dinv, curV, pkV);
  k_scatter_ent<<<cdiv(E1,256),256,0,stream>>>(ee, eel, E1, curE, pkE);

  // weight prep
  k_transpose<<<64,256,0,stream>>>(G1, G1t);
  k_transpose<<<64,256,0,stream>>>(G2, G2t);
  k_transpose<<<64,256,0,stream>>>(Wl1, Wl1t);
  k_transpose<<<64,256,0,stream>>>(Wl2, Wl2t);
  k_wprod<<<128,256,0,stream>>>(W, G1, WvG1t, WaG1);
  k_attP<<<cdiv(NA*128,256),256,0,stream>>>(att, WaG1, attP, NA);
  k_csc<<<1,128,0,stream>>>(We1, ae1, We2, ae2, csc);

  // h0 = nodes0 @ gcn1_W  (folded)
  k_gemm<<<cdiv(NV,128),256,0,stream>>>(valf, WvG1t, valP, NV);
  k_gemm<<<cdiv(NEnt,128),256,0,stream>>>(entf, G1t, B, NEnt);
  k_gather<<<cdiv(T,4),256,0,stream>>>(trip, attP, valP, B, T, NEnt);

  // GCN1 (full N) -> A
  k_gcn_csr<<<cdiv(N,4),256,0,stream>>>(rpV, pkV, B, dinv, g1b, A, N);

  // GCN2 (only dst < NEnt needed) : h2 = A@G2 -> B ; gather -> A[:NEnt]
  k_gemm<<<cdiv(N,128),256,0,stream>>>(A, G2t, B, N);
  k_gcn_csr<<<cdiv(NEnt,4),256,0,stream>>>(rpV, pkV, B, dinv, g2b, A, NEnt);

  // GAT (both layers fused; only rows < NEnt)
  k_gemm<<<cdiv(NEnt,128),256,0,stream>>>(A, Wl1t, hg1, NEnt);
  k_gemm<<<cdiv(NEnt,128),256,0,stream>>>(A, Wl2t, hg2, NEnt);
  k_dots<<<cdiv(NEnt,4),256,0,stream>>>(hg1, hg2, as1v, ad1v, as2v, ad2v, als1, ald1, als2, ald2, NEnt);
  k_gat_csr<<<cdiv(NEnt,4),256,0,stream>>>(rpE, pkE, hg1, hg2, als1, ald1, als2, ald2,
                                           loopA, csc, b1, b2, entf, (float*)d_out, NEnt);
}

// Round 4
// 1069.626 us; speedup vs baseline: 2.3115x; 1.1089x over previous
//
#include <hip/hip_runtime.h>
#include <hip/hip_bf16.h>

typedef __attribute__((ext_vector_type(8))) short short8;
typedef __attribute__((ext_vector_type(4))) float f32x4;

__device__ __forceinline__ float b2f(ushort u){ unsigned v = ((unsigned)u)<<16; float f; __builtin_memcpy(&f,&v,4); return f; }
__device__ __forceinline__ ushort f2b(float x){ __hip_bfloat16 h = __float2bfloat16(x); ushort u; __builtin_memcpy(&u,&h,2); return u; }
__device__ __forceinline__ float lrelu(float x){ return x >= 0.f ? x : 0.2f*x; }

// ---------------- small prep kernels ----------------

__global__ void k_zero(int* degi, long N, int* cntE, float* loopS, long NE){
  long i = (long)blockIdx.x*256 + threadIdx.x;
  if (i < N) degi[i] = 0;
  if (i < NE) { cntE[i] = 0; loopS[i] = 0.f; }
}

__global__ void k_deg_val(const int* __restrict__ ve, long E2, int* degi){
  long e = (long)blockIdx.x*256 + threadIdx.x;
  if (e < E2) atomicAdd(&degi[ve[2*e+1]], 1);
}

__global__ void k_deg_ent(const int* __restrict__ ee, const float* __restrict__ lab, long E1, int* cntE, float* loopS){
  long e = (long)blockIdx.x*256 + threadIdx.x;
  if (e < E1){ int d = ee[2*e+1]; atomicAdd(&cntE[d],1); atomicAdd(&loopS[d], lab[e]); }
}

__global__ void k_dinv(const int* degi, float* dinv, long N, const int* cntE, const float* loopS, float* loopA, long NE){
  long n = (long)blockIdx.x*256 + threadIdx.x;
  if (n < N) dinv[n] = rsqrtf((float)(degi[n]+1));
  if (n < NE) loopA[n] = loopS[n] / fmaxf((float)cntE[n], 1.f);
}

// ---------------- prefix-sum (CSR rowptr) ----------------
__global__ void k_scan1(const int* __restrict__ deg, long L, int* __restrict__ ps, int* __restrict__ bsum){
  __shared__ int s[256];
  long base = (long)blockIdx.x*1024;
  int t = threadIdx.x;
  int v[4]; int sum = 0;
#pragma unroll
  for (int i=0;i<4;++i){ long idx = base + t*4 + i; v[i] = (idx<L) ? deg[idx] : 0; sum += v[i]; }
  s[t] = sum; __syncthreads();
  for (int off=1; off<256; off<<=1){
    int x = 0;
    if (t>=off) x = s[t-off];
    __syncthreads();
    if (t>=off) s[t] += x;
    __syncthreads();
  }
  int run = s[t] - sum;
#pragma unroll
  for (int i=0;i<4;++i){ long idx = base + t*4 + i; if (idx<L) ps[idx] = run; run += v[i]; }
  if (t==255) bsum[blockIdx.x] = s[255];
}

__global__ void k_scan2(const int* __restrict__ bsum, int* __restrict__ boff, int nb){
  __shared__ int s[512];
  int t = threadIdx.x;
  int v = (t<nb) ? bsum[t] : 0;
  s[t] = v; __syncthreads();
  for (int off=1; off<512; off<<=1){
    int x = 0;
    if (t>=off) x = s[t-off];
    __syncthreads();
    if (t>=off) s[t] += x;
    __syncthreads();
  }
  if (t<nb) boff[t] = s[t] - v;
}

__global__ void k_scan3(int* __restrict__ ps, int* __restrict__ cur, const int* __restrict__ boff, long L, int E){
  long i = (long)blockIdx.x*256 + threadIdx.x;
  if (i < L){ int v = ps[i] + boff[i>>10]; ps[i] = v; cur[i] = v; }
  if (i == L) ps[L] = E;
}

__global__ void k_scatter_val(const int* __restrict__ ve, long E2, const float* __restrict__ dinv,
                              int* __restrict__ cur, int2* __restrict__ pk){
  long e = (long)blockIdx.x*256 + threadIdx.x;
  if (e >= E2) return;
  int s = ve[2*e], d = ve[2*e+1];
  int pos = atomicAdd(&cur[d], 1);
  int2 p; p.x = s; p.y = __float_as_int(dinv[s]);
  pk[pos] = p;
}

__global__ void k_scatter_ent(const int* __restrict__ ee, const float* __restrict__ lab, long E1,
                              int* __restrict__ cur, int2* __restrict__ pk){
  long e = (long)blockIdx.x*256 + threadIdx.x;
  if (e >= E1) return;
  int s = ee[2*e], d = ee[2*e+1];
  int pos = atomicAdd(&cur[d], 1);
  int2 p; p.x = s; p.y = __float_as_int(lab[e]);
  pk[pos] = p;
}

// ---------------- tiny weight-chain prep ----------------

// Wvt[n*128+k] = bf16(W[(128+k)*128+n])
__global__ void k_wvt(const float* __restrict__ W, ushort* __restrict__ Wvt){
  int o = blockIdx.x*256 + threadIdx.x; int k = o>>7, n = o&127;
  Wvt[n*128+k] = f2b(W[(128+k)*128+n]);
}

// C = A@B (128x128 fp32)
__global__ void k_mm128(const float* __restrict__ A, const float* __restrict__ B, float* __restrict__ C){
  int o = blockIdx.x*256 + threadIdx.x; int k = o>>7, n = o&127;
  float s = 0.f;
  for (int j=0;j<128;++j) s += A[k*128+j]*B[j*128+n];
  C[o] = s;
}

// Mt[n*128+k] = bf16(sum_j P[k][j]*Wl[j][n])   (transposed for GEMM B-operand)
__global__ void k_mmt(const float* __restrict__ P, const float* __restrict__ Wl, ushort* __restrict__ Mt){
  int o = blockIdx.x*256 + threadIdx.x; int k = o>>7, n = o&127;
  float s = 0.f;
  for (int j=0;j<128;++j) s += P[k*128+j]*Wl[j*128+n];
  Mt[n*128+k] = f2b(s);
}

// u_k = (g1b@G2)@Wl_k ; v_k = g2b@Wl_k
__global__ void k_uv(const float* g1b, const float* g2b, const float* G2,
                     const float* Wl1, const float* Wl2,
                     float* u1, float* v1, float* u2, float* v2){
  __shared__ float t[128];
  int n = threadIdx.x; // 128
  float s = 0.f;
  for (int k=0;k<128;++k) s += g1b[k]*G2[k*128+n];
  t[n] = s; __syncthreads();
  float a=0.f,b=0.f,c=0.f,dd=0.f;
  for (int j=0;j<128;++j){
    float w1 = Wl1[j*128+n], w2 = Wl2[j*128+n];
    a += t[j]*w1; c += t[j]*w2; b += g2b[j]*w1; dd += g2b[j]*w2;
  }
  u1[n]=a; v1[n]=b; u2[n]=c; v2[n]=dd;
}

__global__ void k_csc(const float* We1, const float* ae1, const float* We2, const float* ae2, float* csc){
  int t = threadIdx.x; // 128
  __shared__ float s1[128], s2[128];
  s1[t] = We1[t]*ae1[t];
  s2[t] = We2[t]*ae2[t];
  __syncthreads();
  for (int off=64; off>0; off>>=1){ if (t<off){ s1[t]+=s1[t+off]; s2[t]+=s2[t+off]; } __syncthreads(); }
  if (t==0){ csc[0]=s1[0]; csc[1]=s2[0]; }
}

// attP[a][n] = sum_j att[a][j] * W[j][n]   (W rows 0..127 = attribute part)
__global__ void k_attP(const float* __restrict__ att, const float* __restrict__ W, float* attP, long NA){
  long o = (long)blockIdx.x*256 + threadIdx.x;
  if (o >= NA*128) return;
  long a = o>>7; int n = o&127;
  float s = 0.f;
  for (int j=0;j<128;++j) s += att[a*128+j]*W[j*128+n];
  attP[o] = s;
}

// fp32 -> bf16 bulk cast (n4 float4 groups)
__global__ void k_cast(const float* __restrict__ in, ushort* __restrict__ out, long n4){
  long i = (long)blockIdx.x*256 + threadIdx.x;
  if (i >= n4) return;
  float4 v = ((const float4*)in)[i];
  ushort4 o; o.x=f2b(v.x); o.y=f2b(v.y); o.z=f2b(v.z); o.w=f2b(v.w);
  ((ushort4*)out)[i] = o;
}

// ---------------- MFMA GEMM: C[M x 128] (bf16) = A[M x 128] @ Bt^T (+ rs*u + v) ----------------
template<bool AF32>
__global__ __launch_bounds__(256) void k_gemm(const void* __restrict__ Ap, const ushort* __restrict__ Bt,
                                              ushort* __restrict__ C, long M, int ostride, int ooff,
                                              const float* __restrict__ u, const float* __restrict__ v,
                                              const float* __restrict__ rs){
  __shared__ ushort As[128*128];
  __shared__ ushort Bs[128*128];
  int tid = threadIdx.x;
  long m0 = (long)blockIdx.x * 128;
  {
    const int4* Bg = (const int4*)Bt;
#pragma unroll
    for (int it=0; it<8; ++it){
      int chunk = tid + it*256;
      int row = chunk >> 4, c = chunk & 15;
      int4 vv = Bg[chunk];
      *(int4*)&Bs[(row<<7) + (((c ^ row) & 15)<<3)] = vv;
    }
  }
  if (AF32){
    const float4* Ag = (const float4*)Ap;
#pragma unroll
    for (int it=0; it<16; ++it){
      int chunk = tid + it*256;
      int row = chunk >> 5, q = chunk & 31;
      long grow = m0 + row;
      float4 vv = make_float4(0.f,0.f,0.f,0.f);
      if (grow < M) vv = Ag[grow*32 + q];
      ushort4 h; h.x=f2b(vv.x); h.y=f2b(vv.y); h.z=f2b(vv.z); h.w=f2b(vv.w);
      int c16 = q >> 1, half = q & 1;
      *(ushort4*)&As[(row<<7) + (((c16 ^ row)&15)<<3) + (half<<2)] = h;
    }
  } else {
    const int4* Ag = (const int4*)Ap;
#pragma unroll
    for (int it=0; it<8; ++it){
      int chunk = tid + it*256;
      int row = chunk >> 4, c = chunk & 15;
      long grow = m0 + row;
      int4 vv = make_int4(0,0,0,0);
      if (grow < M) vv = Ag[grow*16 + c];
      *(int4*)&As[(row<<7) + (((c ^ row)&15)<<3)] = vv;
    }
  }
  __syncthreads();
  int wave = tid >> 6, lane = tid & 63;
  int wm = (wave & 1) << 6, wn = (wave >> 1) << 6;
  int l15 = lane & 15, quad = lane >> 4;
  f32x4 acc[4][4] = {};
#pragma unroll
  for (int kk=0; kk<4; ++kk){
    int ch = (kk<<2) + quad;
    short8 a[4], b[4];
#pragma unroll
    for (int i=0;i<4;++i){ int r = wm + (i<<4) + l15; a[i] = *(const short8*)&As[(r<<7) + (((ch ^ r)&15)<<3)]; }
#pragma unroll
    for (int j=0;j<4;++j){ int r = wn + (j<<4) + l15; b[j] = *(const short8*)&Bs[(r<<7) + (((ch ^ r)&15)<<3)]; }
#pragma unroll
    for (int i=0;i<4;++i)
#pragma unroll
      for (int j=0;j<4;++j)
        acc[i][j] = __builtin_amdgcn_mfma_f32_16x16x32_bf16(a[i], b[j], acc[i][j], 0,0,0);
  }
#pragma unroll
  for (int i=0;i<4;++i){
#pragma unroll
    for (int r=0;r<4;++r){
      long grow = m0 + wm + (i<<4) + (quad<<2) + r;
      if (grow < M){
        float rsv = rs ? rs[grow] : 0.f;
#pragma unroll
        for (int j=0;j<4;++j){
          int col = wn + (j<<4) + l15;
          float x = acc[i][j][r];
          if (u) x += rsv*u[col] + v[col];
          C[grow*(long)ostride + ooff + col] = f2b(x);
        }
      }
    }
  }
}

// ---------------- gather / aggregation ----------------

__global__ void k_gather(const int* __restrict__ trip, const float* __restrict__ attP,
                         const ushort* __restrict__ valP, ushort* __restrict__ h0, long T, long NEnt){
  int w = threadIdx.x >> 6, lane = threadIdx.x & 63;
  long t = (long)blockIdx.x*4 + w;
  if (t >= T) return;
  int a = trip[3*t+2], v = trip[3*t+1];
  float2 ap = ((const float2*)(attP + (long)a*128))[lane];
  unsigned vp = ((const unsigned*)(valP + (long)v*128))[lane];
  ushort2 o;
  o.x = f2b(ap.x + b2f((ushort)(vp & 0xffff)));
  o.y = f2b(ap.y + b2f((ushort)(vp >> 16)));
  ((ushort2*)(h0 + (NEnt + t)*128))[lane] = o;
}

// out[d] = dinv[d]^2*h[d] + sum_e dinv[s]*dinv[d]*h[s]   (bf16 out; optional rowsum rs)
__global__ void k_agg(const int* __restrict__ rp, const int2* __restrict__ pk,
                      const ushort* __restrict__ h, const float* __restrict__ dinv,
                      ushort* __restrict__ outH, float* __restrict__ rs, long R){
  int w = threadIdx.x>>6, lane = threadIdx.x&63;
  long d = (long)blockIdx.x*4 + w;
  if (d >= R) return;
  int r0 = rp[d], r1 = rp[d+1];
  float dv = dinv[d];
  unsigned hv = ((const unsigned*)(h + d*128))[lane];
  float wself = dv*dv;
  float ax = wself*b2f((ushort)(hv&0xffff));
  float ay = wself*b2f((ushort)(hv>>16));
  float wsum = wself;
  for (int e = r0; e < r1; ++e){
    int2 p = pk[e];
    float wgt = dv * __int_as_float(p.y);
    unsigned sv = ((const unsigned*)(h + (long)p.x*128))[lane];
    ax += wgt * b2f((ushort)(sv&0xffff));
    ay += wgt * b2f((ushort)(sv>>16));
    wsum += wgt;
  }
  ushort2 o; o.x = f2b(ax); o.y = f2b(ay);
  ((ushort2*)(outH + d*128))[lane] = o;
  if (rs && lane==0) rs[d] = wsum;
}

// per-node attention dots from interleaved hgI rows -> packed float2 (layer1, layer2)
__global__ void k_dots(const uint2* __restrict__ hgI,
                       const float* vs1, const float* vd1, const float* vs2, const float* vd2,
                       float2* __restrict__ alsP, float2* __restrict__ aldP, long R){
  int w = threadIdx.x>>6, lane = threadIdx.x&63;
  long n = (long)blockIdx.x*4 + w;
  if (n >= R) return;
  bool lo = lane < 32; int l = lo ? lane : lane-32;
  uint2 hv = hgI[n*64 + lane];
  float4 us = lo ? ((const float4*)vs1)[l] : ((const float4*)vs2)[l];
  float4 ud = lo ? ((const float4*)vd1)[l] : ((const float4*)vd2)[l];
  float h0 = b2f((ushort)(hv.x&0xffff)), h1 = b2f((ushort)(hv.x>>16));
  float h2 = b2f((ushort)(hv.y&0xffff)), h3 = b2f((ushort)(hv.y>>16));
  float ps = h0*us.x + h1*us.y + h2*us.z + h3*us.w;
  float pd = h0*ud.x + h1*ud.y + h2*ud.z + h3*ud.w;
  for (int o=16;o>0;o>>=1){ ps += __shfl_down(ps,o); pd += __shfl_down(pd,o); }
  if (lane==0) { alsP[n].x = ps; aldP[n].x = pd; }
  if (lane==32){ alsP[n].y = ps; aldP[n].y = pd; }
}

// Fused dual-layer GAT via CSR gather over interleaved hgI; writes final out (+b1+b2+ent_feats)
__global__ void k_gat_csr(const int* __restrict__ rp, const int2* __restrict__ pk,
      const uint2* __restrict__ hgI,
      const float2* __restrict__ alsP, const float2* __restrict__ aldP,
      const float* __restrict__ loopA, const float* __restrict__ csc,
      const float* __restrict__ b1, const float* __restrict__ b2v,
      const float* __restrict__ entf, float* __restrict__ out, long R){
  int w = threadIdx.x>>6, lane = threadIdx.x&63;
  long d = (long)blockIdx.x*4 + w;
  if (d >= R) return;
  int r0 = rp[d], r1 = rp[d+1], ne = r1 - r0;
  float c1 = csc[0], c2 = csc[1];
  float2 aldd = aldP[d];
  float2 alsd = alsP[d];
  float la = loopA[d];
  float a1s = lrelu(alsd.x + aldd.x + c1*la);
  float a2s = lrelu(alsd.y + aldd.y + c2*la);
  // batch0 edge alphas, cached in registers
  float a1c = -1e30f, a2c = -1e30f; int srcc = 0;
  if (lane < ne){
    int2 p = pk[r0+lane];
    float lab = __int_as_float(p.y);
    float2 av = alsP[p.x];
    a1c = lrelu(av.x + aldd.x + c1*lab);
    a2c = lrelu(av.y + aldd.y + c2*lab);
    srcc = p.x;
  }
  float m1 = a1c, m2 = a2c;
  for (int o=32;o>0;o>>=1){ m1 = fmaxf(m1,__shfl_down(m1,o)); m2 = fmaxf(m2,__shfl_down(m2,o)); }
  m1 = fmaxf(__shfl(m1,0), a1s); m2 = fmaxf(__shfl(m2,0), a2s);
  for (int base=64; base<ne; base+=64){   // rare (deg>64)
    int i = base+lane; float x1=-1e30f, x2=-1e30f;
    if (i<ne){ int2 p = pk[r0+i]; float lab = __int_as_float(p.y); float2 av = alsP[p.x];
      x1 = lrelu(av.x + aldd.x + c1*lab); x2 = lrelu(av.y + aldd.y + c2*lab); }
    for (int o=32;o>0;o>>=1){ x1 = fmaxf(x1,__shfl_down(x1,o)); x2 = fmaxf(x2,__shfl_down(x2,o)); }
    m1 = fmaxf(m1, __shfl(x1,0)); m2 = fmaxf(m2, __shfl(x2,0));
  }
  float e1s = __expf(a1s-m1), e2s = __expf(a2s-m2);
  float z1 = e1s, z2 = e2s;
  bool lo = lane < 32;
  uint2 hv = hgI[d*64 + lane];
  float ws0 = lo ? e1s : e2s;
  float ac0 = ws0*b2f((ushort)(hv.x&0xffff));
  float ac1 = ws0*b2f((ushort)(hv.x>>16));
  float ac2 = ws0*b2f((ushort)(hv.y&0xffff));
  float ac3 = ws0*b2f((ushort)(hv.y>>16));
  {
    float e1 = (lane<ne) ? __expf(a1c-m1) : 0.f;
    float e2 = (lane<ne) ? __expf(a2c-m2) : 0.f;
    int lim = ne < 64 ? ne : 64;
    for (int j=0;j<lim;++j){
      float f1 = __shfl(e1,j), f2 = __shfl(e2,j); int sj = __shfl(srcc,j);
      z1 += f1; z2 += f2;
      uint2 vv = hgI[(long)sj*64 + lane];
      float f = lo ? f1 : f2;
      ac0 += f*b2f((ushort)(vv.x&0xffff));
      ac1 += f*b2f((ushort)(vv.x>>16));
      ac2 += f*b2f((ushort)(vv.y&0xffff));
      ac3 += f*b2f((ushort)(vv.y>>16));
    }
  }
  for (int base=64; base<ne; base+=64){   // rare
    int i = base+lane; float e1=0.f, e2=0.f; int src = 0;
    if (i<ne){ int2 p = pk[r0+i]; float lab = __int_as_float(p.y); float2 av = alsP[p.x];
      e1 = __expf(lrelu(av.x + aldd.x + c1*lab)-m1);
      e2 = __expf(lrelu(av.y + aldd.y + c2*lab)-m2);
      src = p.x; }
    int lim = (ne-base < 64) ? (ne-base) : 64;
    for (int j=0;j<lim;++j){
      float f1 = __shfl(e1,j), f2 = __shfl(e2,j); int sj = __shfl(src,j);
      z1 += f1; z2 += f2;
      uint2 vv = hgI[(long)sj*64 + lane];
      float f = lo ? f1 : f2;
      ac0 += f*b2f((ushort)(vv.x&0xffff));
      ac1 += f*b2f((ushort)(vv.x>>16));
      ac2 += f*b2f((ushort)(vv.y&0xffff));
      ac3 += f*b2f((ushort)(vv.y>>16));
    }
  }
  float iz = lo ? 1.f/(z1+1e-16f) : 1.f/(z2+1e-16f);
  ac0 *= iz; ac1 *= iz; ac2 *= iz; ac3 *= iz;
  int pl = lane ^ 32;
  float p0 = __shfl(ac0, pl), p1 = __shfl(ac1, pl), p2 = __shfl(ac2, pl), p3 = __shfl(ac3, pl);
  if (lo){
    float4 bb1 = ((const float4*)b1)[lane];
    float4 bb2 = ((const float4*)b2v)[lane];
    float4 ef  = ((const float4*)(entf + d*128))[lane];
    float4 o;
    o.x = ac0 + p0 + bb1.x + bb2.x + ef.x;
    o.y = ac1 + p1 + bb1.y + bb2.y + ef.y;
    o.z = ac2 + p2 + bb1.z + bb2.z + ef.z;
    o.w = ac3 + p3 + bb1.w + bb2.w + ef.w;
    ((float4*)(out + d*128))[lane] = o;
  }
}

// ---------------- host ----------------

extern "C" void kernel_launch(void* const* d_in, const int* in_sizes, int n_in,
                              void* d_out, int out_size, void* d_ws, size_t ws_size,
                              hipStream_t stream) {
  const int*   trip = (const int*)d_in[0];
  const int*   ee   = (const int*)d_in[1];
  const float* eel  = (const float*)d_in[2];
  const int*   ve   = (const int*)d_in[3];
  const float* att  = (const float*)d_in[5];
  const float* valf = (const float*)d_in[6];
  const float* entf = (const float*)d_in[7];
  const float* W    = (const float*)d_in[8];
  const float* G1   = (const float*)d_in[9];
  const float* g1b  = (const float*)d_in[10];
  const float* G2   = (const float*)d_in[11];
  const float* g2b  = (const float*)d_in[12];
  const float* Wl1  = (const float*)d_in[13];
  const float* as1v = (const float*)d_in[14];
  const float* ad1v = (const float*)d_in[15];
  const float* We1  = (const float*)d_in[16];
  const float* ae1  = (const float*)d_in[17];
  const float* b1   = (const float*)d_in[18];
  const float* Wl2  = (const float*)d_in[19];
  const float* as2v = (const float*)d_in[20];
  const float* ad2v = (const float*)d_in[21];
  const float* We2  = (const float*)d_in[22];
  const float* ae2  = (const float*)d_in[23];
  const float* b2   = (const float*)d_in[24];

  long T    = in_sizes[0]/3;
  long E1   = in_sizes[1]/2;
  long E2   = in_sizes[3]/2;
  long NA   = in_sizes[5]/128;
  long NV   = in_sizes[6]/128;
  long NEnt = in_sizes[7]/128;
  long N    = NEnt + T;

  size_t off = 0;
  auto alloc = [&](size_t bytes)->char*{
    char* p = (char*)d_ws + off; off = (off + bytes + 255) & ~(size_t)255; return p;
  };
  ushort* nodes0 = (ushort*)alloc((size_t)N*128*2);   // later reused as hgI (NEnt*256 ushorts)
  ushort* y1     = (ushort*)alloc((size_t)N*128*2);   // valP overlays this before y1 is written
  ushort* y2     = (ushort*)alloc((size_t)NEnt*128*2);
  float*  attP   = (float*)alloc((size_t)NA*128*4);
  int*    degi   = (int*)alloc(N*4);
  float*  dinv   = (float*)alloc(N*4);
  int*    cntE   = (int*)alloc(NEnt*4);
  float*  loopS  = (float*)alloc(NEnt*4);
  float*  loopA  = (float*)alloc(NEnt*4);
  float2* alsP   = (float2*)alloc(NEnt*8);
  float2* aldP   = (float2*)alloc(NEnt*8);
  float*  rs     = (float*)alloc(NEnt*4);
  int*    rpV    = (int*)alloc((N+1)*4);
  int*    curV   = (int*)alloc(N*4);
  int2*   pkV    = (int2*)alloc((size_t)E2*8);
  int*    rpE    = (int*)alloc((NEnt+1)*4);
  int*    curE   = (int*)alloc(NEnt*4);
  int2*   pkE    = (int2*)alloc((size_t)E1*8);
  int*    bsumV  = (int*)alloc(512*4);
  int*    boffV  = (int*)alloc(512*4);
  int*    bsumE  = (int*)alloc(512*4);
  int*    boffE  = (int*)alloc(512*4);
  ushort* Wvt    = (ushort*)alloc(16384*2);
  float*  P      = (float*)alloc(16384*4);
  ushort* M1t    = (ushort*)alloc(16384*2);
  ushort* M2t    = (ushort*)alloc(16384*2);
  float*  u1     = (float*)alloc(128*4);
  float*  v1     = (float*)alloc(128*4);
  float*  u2     = (float*)alloc(128*4);
  float*  v2     = (float*)alloc(128*4);
  float*  csc    = (float*)alloc(256);

  ushort* valP = y1;                 // dead before y1 is written
  ushort* hgI  = nodes0;             // dead after y1 aggregation

  auto cdiv = [](long a, long b)->int{ return (int)((a + b - 1)/b); };
  int nbV = cdiv(N, 1024), nbE = cdiv(NEnt, 1024);

  // degrees / loop_attr
  k_zero<<<cdiv(N,256),256,0,stream>>>(degi, N, cntE, loopS, NEnt);
  k_deg_val<<<cdiv(E2,256),256,0,stream>>>(ve, E2, degi);
  k_deg_ent<<<cdiv(E1,256),256,0,stream>>>(ee, eel, E1, cntE, loopS);
  k_dinv<<<cdiv(N,256),256,0,stream>>>(degi, dinv, N, cntE, loopS, loopA, NEnt);

  // CSR build
  k_scan1<<<nbV,256,0,stream>>>(degi, N, rpV, bsumV);
  k_scan2<<<1,512,0,stream>>>(bsumV, boffV, nbV);
  k_scan3<<<cdiv(N+1,256),256,0,stream>>>(rpV, curV, boffV, N, (int)E2);
  k_scan1<<<nbE,256,0,stream>>>(cntE, NEnt, rpE, bsumE);
  k_scan2<<<1,512,0,stream>>>(bsumE, boffE, nbE);
  k_scan3<<<cdiv(NEnt+1,256),256,0,stream>>>(rpE, curE, boffE, NEnt, (int)E1);
  k_scatter_val<<<cdiv(E2,256),256,0,stream>>>(ve, E2, dinv, curV, pkV);
  k_scatter_ent<<<cdiv(E1,256),256,0,stream>>>(ee, eel, E1, curE, pkE);

  // tiny weight chains: P=G1@G2, M_k = P@Wl_k (bf16,T), u_k=(g1b@G2)@Wl_k, v_k=g2b@Wl_k
  k_wvt<<<64,256,0,stream>>>(W, Wvt);
  k_mm128<<<64,256,0,stream>>>(G1, G2, P);
  k_mmt<<<64,256,0,stream>>>(P, Wl1, M1t);
  k_mmt<<<64,256,0,stream>>>(P, Wl2, M2t);
  k_uv<<<1,128,0,stream>>>(g1b, g2b, G2, Wl1, Wl2, u1, v1, u2, v2);
  k_csc<<<1,128,0,stream>>>(We1, ae1, We2, ae2, csc);
  k_attP<<<cdiv(NA*128,256),256,0,stream>>>(att, W, attP, NA);

  // nodes0 (bf16): ent rows = ent_feats; val rows = attP[a] + (valf@Wv)[v]
  k_gemm<true><<<cdiv(NV,128),256,0,stream>>>(valf, Wvt, valP, NV, 128, 0, nullptr, nullptr, nullptr);
  k_cast<<<cdiv(NEnt*32,256),256,0,stream>>>(entf, nodes0, NEnt*32);
  k_gather<<<cdiv(T,4),256,0,stream>>>(trip, attP, valP, nodes0, T, NEnt);

  // y1 = A(nodes0) over all N ; y2 = A(y1) over NEnt rows (+rowsum rs)
  k_agg<<<cdiv(N,4),256,0,stream>>>(rpV, pkV, nodes0, dinv, y1, nullptr, N);
  k_agg<<<cdiv(NEnt,4),256,0,stream>>>(rpV, pkV, y1, dinv, y2, rs, NEnt);

  // hgI rows = [ y2@M1 + rs*u1 + v1 | y2@M2 + rs*u2 + v2 ]
  k_gemm<false><<<cdiv(NEnt,128),256,0,stream>>>(y2, M1t, (ushort*)hgI, NEnt, 256, 0,   u1, v1, rs);
  k_gemm<false><<<cdiv(NEnt,128),256,0,stream>>>(y2, M2t, (ushort*)hgI, NEnt, 256, 128, u2, v2, rs);

  // GAT attention scalars + fused dual-layer aggregation -> final output
  k_dots<<<cdiv(NEnt,4),256,0,stream>>>((const uint2*)hgI, as1v, ad1v, as2v, ad2v, alsP, aldP, NEnt);
  k_gat_csr<<<cdiv(NEnt,4),256,0,stream>>>(rpE, pkE, (const uint2*)hgI, alsP, aldP,
                                           loopA, csc, b1, b2, entf, (float*)d_out, NEnt);
}